// Round 5
// 757.313 us; speedup vs baseline: 1.0046x; 1.0046x over previous
//
#include <hip/hip_runtime.h>
#include <math.h>

// FunctionSet: per-point categorical choice (JAX threefry, key=42) then
// affine+sine transform. Output (n,3) f32.
//
// RNG scheme: PARTITIONABLE threefry (jax default >= 0.4.36):
//   m = 16*i + j ; (r0,r1) = threefry2x32(k=(0,42), x0=hi32(m)=0, x1=lo32(m)=m)
//   bits = r0 ^ r1
// FALLBACK (if absmax ~ 2.7 => wrong scheme): legacy split-iota scheme:
//   half = n*16/2; pair (m, m+half): x0=m, x1=m+half; out[m]=r0, out[m+half]=r1.
//
// choice = argmax_j  -log(-log u_j) + log p_j  ==  argmin_j (-log u_j)/p_j
// computed in f64 to match an f64 reference's decisions.
// u = k * 2^-23 exactly (k = bits>>9), so -log u = 23*ln2 - log(k): ONE libm
// log call, no bit tricks. (Round 4: deliberately boring build — previous 3
// rounds died with broker-layer Trio errors; ruling out content-triggered
// toolchain/harness pathology.)
//
// SESSION R5 BISECT: rounds R1-R4 (table-log LUT variant) all died in
// broker-layer Trio nursery errors with zero compile/run evidence. This
// submission is the byte-exact R0 baseline that PASSED in this session
// (760.8us). If it fails -> infra confirmed. If it passes -> content of the
// LUT variant triggers the harness failure; bisect init vs hot-loop next.

__device__ __forceinline__ void tf_round(uint32_t& x0, uint32_t& x1, int r) {
  x0 += x1;
  x1 = (x1 << r) | (x1 >> (32 - r));
  x1 ^= x0;
}

__device__ __forceinline__ uint2 threefry(uint32_t x0, uint32_t x1) {
  const uint32_t k0 = 0u, k1 = 42u, k2 = 0x1BD11BDAu ^ 0u ^ 42u;
  x0 += k0; x1 += k1;
  tf_round(x0, x1, 13); tf_round(x0, x1, 15); tf_round(x0, x1, 26); tf_round(x0, x1, 6);
  x0 += k1; x1 += k2 + 1u;
  tf_round(x0, x1, 17); tf_round(x0, x1, 29); tf_round(x0, x1, 16); tf_round(x0, x1, 24);
  x0 += k2; x1 += k0 + 2u;
  tf_round(x0, x1, 13); tf_round(x0, x1, 15); tf_round(x0, x1, 26); tf_round(x0, x1, 6);
  x0 += k0; x1 += k1 + 3u;
  tf_round(x0, x1, 17); tf_round(x0, x1, 29); tf_round(x0, x1, 16); tf_round(x0, x1, 24);
  x0 += k1; x1 += k2 + 4u;
  tf_round(x0, x1, 13); tf_round(x0, x1, 15); tf_round(x0, x1, 26); tf_round(x0, x1, 6);
  x0 += k2; x1 += k0 + 5u;
  return make_uint2(x0, x1);
}

__global__ __launch_bounds__(256) void fs_kernel(
    const float* __restrict__ points, const float* __restrict__ probs,
    const float* __restrict__ Amat, const float* __restrict__ bvec,
    const float* __restrict__ wvec, const float* __restrict__ colors,
    float* __restrict__ out, int n)
{
  __shared__ double invp[16];
  __shared__ float sP[9][16];   // A00 A01 A10 A11 b0 b1 w0 w1 color

  const int t = threadIdx.x;
  if (t < 16) invp[t] = 1.0 / (double)probs[t];
  if (t < 144) {
    int f = t & 15, q = t >> 4;
    float val;
    if (q < 4)       val = Amat[f * 4 + q];
    else if (q == 4) val = bvec[f * 2];
    else if (q == 5) val = bvec[f * 2 + 1];
    else if (q == 6) val = wvec[f * 2];
    else if (q == 7) val = wvec[f * 2 + 1];
    else             val = colors[f];
    sP[q][f] = val;
  }
  __syncthreads();

  const int i = blockIdx.x * 256 + t;
  if (i >= n) return;
  const uint32_t base = (uint32_t)i << 4;

  double best = 1.0e300;
  int bf = 0;

  const double LN2x23 = 15.9423851528787422210;   // 23*ln2
  const double VMAX   = 87.3365447505531089800;   // -log(2^-126), k==0 case

  for (int j = 0; j < 16; ++j) {
    uint2 rr = threefry(0u, base + (uint32_t)j);
    uint32_t bits = rr.x ^ rr.y;
    uint32_t k = bits >> 9;              // u = k * 2^-23 (f32 tiny if k==0)

    double v;
    if (k == 0u) {
      v = VMAX;
    } else {
      v = LN2x23 - log((double)k);       // -log(u), <1 ulp via libm
    }

    double s = v * invp[j];
    if (s < best) { best = s; bf = j; }
  }

  // epilogue: t = A*xy + b ; out = w0*t + w1*sin(t) ; col avg
  float x = points[3 * i];
  float y = points[3 * i + 1];
  float c = points[3 * i + 2];
  float A00 = sP[0][bf], A01 = sP[1][bf], A10 = sP[2][bf], A11 = sP[3][bf];
  float b0 = sP[4][bf], b1 = sP[5][bf];
  float w0 = sP[6][bf], w1 = sP[7][bf], col = sP[8][bf];
  float t0 = A00 * x + A01 * y + b0;
  float t1 = A10 * x + A11 * y + b1;
  float o0 = w0 * t0 + w1 * __sinf(t0);
  float o1 = w0 * t1 + w1 * __sinf(t1);
  float o2 = (c + col) * 0.5f;
  out[3 * i]     = o0;
  out[3 * i + 1] = o1;
  out[3 * i + 2] = o2;
}

extern "C" void kernel_launch(void* const* d_in, const int* in_sizes, int n_in,
                              void* d_out, int out_size, void* d_ws, size_t ws_size,
                              hipStream_t stream) {
  const float* points = (const float*)d_in[0];
  const float* probs  = (const float*)d_in[1];
  const float* Amat   = (const float*)d_in[2];
  const float* bvec   = (const float*)d_in[3];
  const float* wvec   = (const float*)d_in[4];
  const float* colors = (const float*)d_in[5];
  float* out = (float*)d_out;
  int n = in_sizes[0] / 3;
  if (n <= 0) return;
  int nblocks = (n + 255) / 256;
  fs_kernel<<<nblocks, 256, 0, stream>>>(points, probs, Amat, bvec, wvec, colors, out, n);
}